// Round 8
// baseline (211.730 us; speedup 1.0000x reference)
//
#include <hip/hip_runtime.h>

// GCN 2-layer forward, N=100000, E=3200000, 128->16->2.
// Session-2 round-7 (prev 189.1us verified; r5 revert confirmed; fillB uint4
// worth ~-3us). CORRECTION: r5's "115MB write-amp" was confounded -- it was
// the deg atomics' 32B-granule memory-side writes (3.2M x 32B = 102MB), not
// bucket-run amplification. Differencing r5/r7 totals: scatter ~20us,
// fillB ~30us -> the AGG PAIR is the dominant block now.
// This round, two independent changes:
//  1. agg1h2: 4 nodes/wave x 4 groups (mean 4 dep-chain iters, max-of-4
//     degree skew) -> 1 node/wave, 2 halves x 32 groups (mean 1.45 iters,
//     one gather instr packs 64 lane-requests). agg2: 4->2 nodes/wave
//     (32 lanes/node, mean 1.45 iters).
//  2. k_bscan merged into k_fillB (each block scans gcur in LDS; the
//     1-block bscan forced a full pipeline drain). 7 -> 6 launches.
// Validated and kept: fixed-stride regions (RCAP=12288), register-staged
// single-pass scatter, uint4 fillB passes, K-split k_xw1, bf16 hs.
// LESSONS: hot-address global atomicAdd serializes (~23G/s); LDS-atomic
// aggregation 8x worse than sorted gather.
// Algebra: hs = (x@W1)*dinv;
//   h1[d]  = relu(dinv[d]*(sum_nbr hs + hs[d]) + b1), W2 fused -> h2s
//   out[d] = dinv[d]*(sum_nbr h2s + h2s[d]) + b2

#define EPB  8192    // edges per partition block
#define RCAP 12288   // per-bucket region capacity (mean 8192, sigma~90)
#define CAP  16384   // LDS slots per bucket in k_fillB

typedef unsigned int u32;
typedef unsigned short u16;

__device__ __forceinline__ float bflo(u32 u) { return __uint_as_float(u << 16); }
__device__ __forceinline__ float bfhi(u32 u) { return __uint_as_float(u & 0xffff0000u); }
__device__ __forceinline__ u32 pack_bf2(float a, float b) {   // RNE
    u32 ua = __float_as_uint(a); ua = (ua + 0x7fffu + ((ua >> 16) & 1u)) >> 16;
    u32 ub = __float_as_uint(b); ub = (ub + 0x7fffu + ((ub >> 16) & 1u)) >> 16;
    return ua | (ub << 16);
}

// ---------------- init bucket region cursors ----------------
__global__ __launch_bounds__(512) void k_binit(int* __restrict__ gcur, int NBUK) {
    int t = threadIdx.x;
    if (t < NBUK) gcur[t] = t * RCAP;
}

// ---------------- single-pass partition: count+scan+reserve+place ----------
// Edges staged in registers (8x int4) across the scan -> no second global read.
__global__ __launch_bounds__(512) void k_scatter(const int* __restrict__ ei,
                                                 int* __restrict__ gcur,
                                                 u32* __restrict__ part,
                                                 int E, int NBUK) {
    __shared__ int hist[512];   // counts -> scan -> placement cursors
    __shared__ int rbase[512];  // global addr = rbase[b] + local slot j
    __shared__ u32 buf[EPB];
    __shared__ u16 bkt[EPB];
    int tid = threadIdx.x;
    hist[tid] = 0;
    __syncthreads();
    int base = blockIdx.x * EPB;
    int end = base + EPB; if (end > E) end = E;
    int cnt = end - base;
    int nv = cnt >> 2;
    const int4* s4p = (const int4*)(ei + base);
    const int4* d4p = (const int4*)(ei + E + base);
    int4 s4[4], d4[4];
    #pragma unroll
    for (int k = 0; k < 4; ++k) {
        int idx = tid + (k << 9);
        if (idx < nv) {
            s4[k] = s4p[idx];
            d4[k] = d4p[idx];
            atomicAdd(&hist[d4[k].x >> 8], 1);
            atomicAdd(&hist[d4[k].y >> 8], 1);
            atomicAdd(&hist[d4[k].z >> 8], 1);
            atomicAdd(&hist[d4[k].w >> 8], 1);
        }
    }
    for (int e = base + (nv << 2) + tid; e < end; e += 512)   // tail (cnt%4)
        atomicAdd(&hist[ei[E + e] >> 8], 1);
    __syncthreads();
    int v = hist[tid];
    __syncthreads();
    for (int o = 1; o < 512; o <<= 1) {                       // in-place scan
        int t = (tid >= o) ? hist[tid - o] : 0;
        __syncthreads();
        hist[tid] += t;
        __syncthreads();
    }
    int excl = hist[tid] - v;
    int rb = 0;
    if (tid < NBUK && v > 0) rb = atomicAdd(&gcur[tid], v);   // reserve run
    rbase[tid] = rb - excl;
    __syncthreads();
    hist[tid] = excl;            // placement cursor (own slot only)
    __syncthreads();
    #pragma unroll
    for (int k = 0; k < 4; ++k) {
        int idx = tid + (k << 9);
        if (idx < nv) {
            int b, pos;
            b = d4[k].x >> 8; pos = atomicAdd(&hist[b], 1);
            buf[pos] = ((u32)(d4[k].x & 255) << 24) | (u32)s4[k].x; bkt[pos] = (u16)b;
            b = d4[k].y >> 8; pos = atomicAdd(&hist[b], 1);
            buf[pos] = ((u32)(d4[k].y & 255) << 24) | (u32)s4[k].y; bkt[pos] = (u16)b;
            b = d4[k].z >> 8; pos = atomicAdd(&hist[b], 1);
            buf[pos] = ((u32)(d4[k].z & 255) << 24) | (u32)s4[k].z; bkt[pos] = (u16)b;
            b = d4[k].w >> 8; pos = atomicAdd(&hist[b], 1);
            buf[pos] = ((u32)(d4[k].w & 255) << 24) | (u32)s4[k].w; bkt[pos] = (u16)b;
        }
    }
    for (int e = base + (nv << 2) + tid; e < end; e += 512) { // tail re-read
        int s = ei[e], d = ei[E + e];
        int b = d >> 8;
        int pos = atomicAdd(&hist[b], 1);
        buf[pos] = ((u32)(d & 255) << 24) | (u32)s;
        bkt[pos] = (u16)b;
    }
    __syncthreads();
    for (int j = tid; j < cnt; j += 512)
        part[rbase[bkt[j]] + j] = buf[j];                     // ~coalesced runs
}

// ---------------- per-bucket sort by dst; region -> dense csr ---------------
// In-kernel bucket scan (bscan merged); both region passes uint4-vectorized.
__global__ __launch_bounds__(512) void k_fillB(const u32* __restrict__ part,
                                               const int* __restrict__ gcur,
                                               u32* __restrict__ csr,
                                               int* __restrict__ rp,
                                               float* __restrict__ dinv,
                                               int N, int E, int NBUK) {
    __shared__ int hist[256];
    __shared__ int ofs[256];
    __shared__ int bs[512];      // bucket-count scan
    __shared__ u32 srcbuf[CAP];
    int b = blockIdx.x, tid = threadIdx.x;
    if (b == 0 && tid == 0) rp[N] = E;
    int vb = (tid < NBUK) ? (gcur[tid] - tid * RCAP) : 0;
    bs[tid] = vb;
    if (tid < 256) hist[tid] = 0;
    __syncthreads();
    for (int o = 1; o < 512; o <<= 1) {
        int t = (tid >= o) ? bs[tid - o] : 0;
        __syncthreads();
        bs[tid] += t;
        __syncthreads();
    }
    int cnt = gcur[b] - b * RCAP;
    int base_w = bs[b] - cnt;              // dense write base
    int base_r = b * RCAP;                 // region read base (16B aligned)
    int nv = cnt >> 2;
    const uint4* p4 = (const uint4*)(part + base_r);
    for (int t = tid; t < nv; t += 512) {
        uint4 pv = p4[t];
        atomicAdd(&hist[pv.x >> 24], 1);
        atomicAdd(&hist[pv.y >> 24], 1);
        atomicAdd(&hist[pv.z >> 24], 1);
        atomicAdd(&hist[pv.w >> 24], 1);
    }
    for (int j = (nv << 2) + tid; j < cnt; j += 512)
        atomicAdd(&hist[part[base_r + j] >> 24], 1);
    __syncthreads();
    int v = 0;
    if (tid < 256) { v = hist[tid]; ofs[tid] = v; }
    __syncthreads();
    for (int o = 1; o < 256; o <<= 1) {
        int t = 0;
        if (tid < 256 && tid >= o) t = ofs[tid - o];
        __syncthreads();
        if (tid < 256) ofs[tid] += t;
        __syncthreads();
    }
    int excl = 0;
    if (tid < 256) { excl = ofs[tid] - v; hist[tid] = excl; }
    __syncthreads();
    for (int t = tid; t < nv; t += 512) {
        uint4 pv = p4[t];
        int pos;
        pos = atomicAdd(&hist[pv.x >> 24], 1);
        if (pos < CAP) srcbuf[pos] = pv.x & 0xFFFFFFu;
        pos = atomicAdd(&hist[pv.y >> 24], 1);
        if (pos < CAP) srcbuf[pos] = pv.y & 0xFFFFFFu;
        pos = atomicAdd(&hist[pv.z >> 24], 1);
        if (pos < CAP) srcbuf[pos] = pv.z & 0xFFFFFFu;
        pos = atomicAdd(&hist[pv.w >> 24], 1);
        if (pos < CAP) srcbuf[pos] = pv.w & 0xFFFFFFu;
    }
    for (int j = (nv << 2) + tid; j < cnt; j += 512) {
        u32 pv = part[base_r + j];
        int pos = atomicAdd(&hist[pv >> 24], 1);
        if (pos < CAP) srcbuf[pos] = pv & 0xFFFFFFu;
    }
    __syncthreads();
    for (int j = tid; j < cnt; j += 512)
        csr[base_w + j] = srcbuf[j];       // coalesced dense write
    int d = b * 256 + tid;
    if (tid < 256 && d < N) {
        rp[d] = base_w + excl;
        dinv[d] = rsqrtf((float)(v + 1));  // +1 self loop
    }
}

// ---------------- hs[N,16](bf16) = (x@W1)*dinv, K-split, x read once ---------
__global__ __launch_bounds__(256) void k_xw1(const float* __restrict__ x,
                                             const float* __restrict__ W1,
                                             const float* __restrict__ dinv,
                                             u16* __restrict__ hs, int N) {
    __shared__ float w[4 * 516];   // section q = W1 rows 32q..32q+31; +4 pad
    int tid = threadIdx.x;
    for (int t = tid; t < 2048; t += 256)
        w[(t >> 9) * 516 + (t & 511)] = W1[t];
    __syncthreads();
    int t = blockIdx.x * 256 + tid;
    int n = t >> 2, q = t & 3;
    if (n >= N) return;
    const float4* xr = (const float4*)(x + (size_t)n * 128 + q * 32);  // 8 f4
    const float* ws = w + q * 516;
    float acc[16];
    #pragma unroll
    for (int c = 0; c < 16; ++c) acc[c] = 0.f;
    #pragma unroll
    for (int i = 0; i < 8; ++i) {
        float4 u = xr[i];
        const float4* wf = (const float4*)(ws + i * 64);  // rows 4i..4i+3
        #pragma unroll
        for (int c4 = 0; c4 < 4; ++c4) {
            float4 wa = wf[c4];
            float4 wb = wf[4 + c4];
            float4 wc = wf[8 + c4];
            float4 wd = wf[12 + c4];
            int c = c4 * 4;
            acc[c+0] = fmaf(u.x, wa.x, acc[c+0]); acc[c+1] = fmaf(u.x, wa.y, acc[c+1]);
            acc[c+2] = fmaf(u.x, wa.z, acc[c+2]); acc[c+3] = fmaf(u.x, wa.w, acc[c+3]);
            acc[c+0] = fmaf(u.y, wb.x, acc[c+0]); acc[c+1] = fmaf(u.y, wb.y, acc[c+1]);
            acc[c+2] = fmaf(u.y, wb.z, acc[c+2]); acc[c+3] = fmaf(u.y, wb.w, acc[c+3]);
            acc[c+0] = fmaf(u.z, wc.x, acc[c+0]); acc[c+1] = fmaf(u.z, wc.y, acc[c+1]);
            acc[c+2] = fmaf(u.z, wc.z, acc[c+2]); acc[c+3] = fmaf(u.z, wc.w, acc[c+3]);
            acc[c+0] = fmaf(u.w, wd.x, acc[c+0]); acc[c+1] = fmaf(u.w, wd.y, acc[c+1]);
            acc[c+2] = fmaf(u.w, wd.z, acc[c+2]); acc[c+3] = fmaf(u.w, wd.w, acc[c+3]);
        }
    }
    #pragma unroll
    for (int c = 0; c < 16; ++c) {
        acc[c] += __shfl_xor(acc[c], 1);
        acc[c] += __shfl_xor(acc[c], 2);
    }
    float di = dinv[n];
    uint2 o;
    o.x = pack_bf2(acc[4*q+0] * di, acc[4*q+1] * di);
    o.y = pack_bf2(acc[4*q+2] * di, acc[4*q+3] * di);
    ((uint2*)(hs + (size_t)n * 16))[q] = o;
}

// ---------------- fused layer-1 gather + ReLU + W2 projection ----------------
// 1 node/wave: 2 halves (16B uint4) x 32 edge groups; mean 1.45 iterations.
__global__ __launch_bounds__(256) void k_agg1h2(const int* __restrict__ rp,
                                                const int* __restrict__ csr,
                                                const u16* __restrict__ hs,
                                                const float* __restrict__ dinv,
                                                const float* __restrict__ W2,
                                                const float* __restrict__ b1,
                                                float* __restrict__ h2s, int N) {
    int lane = threadIdx.x & 63;
    int wid = blockIdx.x * 4 + (threadIdx.x >> 6);
    if (wid >= N) return;
    int half = lane & 1, g = lane >> 1;            // 16B half, edge group 0..31
    int beg = rp[wid], end = rp[wid + 1];
    float a0 = 0.f, a1 = 0.f, a2 = 0.f, a3 = 0.f;
    float a4 = 0.f, a5 = 0.f, a6 = 0.f, a7 = 0.f;
    for (int j = beg + g; j < end; j += 32) {
        int s = csr[j];
        uint4 u = ((const uint4*)(hs + (size_t)s * 16))[half];
        a0 += bflo(u.x); a1 += bfhi(u.x);
        a2 += bflo(u.y); a3 += bfhi(u.y);
        a4 += bflo(u.z); a5 += bfhi(u.z);
        a6 += bflo(u.w); a7 += bfhi(u.w);
    }
    // reduce across the 32 edge groups (lane bits 1..5)
    #pragma unroll
    for (int o = 2; o <= 32; o <<= 1) {
        a0 += __shfl_xor(a0, o); a1 += __shfl_xor(a1, o);
        a2 += __shfl_xor(a2, o); a3 += __shfl_xor(a3, o);
        a4 += __shfl_xor(a4, o); a5 += __shfl_xor(a5, o);
        a6 += __shfl_xor(a6, o); a7 += __shfl_xor(a7, o);
    }
    uint4 su = ((const uint4*)(hs + (size_t)wid * 16))[half];   // self term
    a0 += bflo(su.x); a1 += bfhi(su.x);
    a2 += bflo(su.y); a3 += bfhi(su.y);
    a4 += bflo(su.z); a5 += bfhi(su.z);
    a6 += bflo(su.w); a7 += bfhi(su.w);
    float di = dinv[wid];
    float4 bA = ((const float4*)b1)[half * 2];
    float4 bB = ((const float4*)b1)[half * 2 + 1];
    float v0 = fmaxf(fmaf(di, a0, bA.x), 0.f);
    float v1 = fmaxf(fmaf(di, a1, bA.y), 0.f);
    float v2 = fmaxf(fmaf(di, a2, bA.z), 0.f);
    float v3 = fmaxf(fmaf(di, a3, bA.w), 0.f);
    float v4 = fmaxf(fmaf(di, a4, bB.x), 0.f);
    float v5 = fmaxf(fmaf(di, a5, bB.y), 0.f);
    float v6 = fmaxf(fmaf(di, a6, bB.z), 0.f);
    float v7 = fmaxf(fmaf(di, a7, bB.w), 0.f);
    const float4* w4 = (const float4*)W2 + half * 4;   // rows half*8..+7
    float4 q0 = w4[0], q1 = w4[1], q2 = w4[2], q3 = w4[3];
    float p0 = v0*q0.x + v1*q0.z + v2*q1.x + v3*q1.z
             + v4*q2.x + v5*q2.z + v6*q3.x + v7*q3.z;
    float p1 = v0*q0.y + v1*q0.w + v2*q1.y + v3*q1.w
             + v4*q2.y + v5*q2.w + v6*q3.y + v7*q3.w;
    p0 += __shfl_xor(p0, 1); p1 += __shfl_xor(p1, 1);  // sum the two halves
    if (lane == 0)
        *(float2*)(h2s + (size_t)wid * 2) = make_float2(p0 * di, p1 * di);
}

// ---------------- layer-2 gather -> out (2 nodes/wave, 32 lanes/node) --------
__global__ __launch_bounds__(256) void k_agg2(const int* __restrict__ rp,
                                              const int* __restrict__ csr,
                                              const float* __restrict__ h2s,
                                              const float* __restrict__ dinv,
                                              const float* __restrict__ b2,
                                              float* __restrict__ out, int N) {
    int lane = threadIdx.x & 63;
    int wid = blockIdx.x * 8 + (threadIdx.x >> 6) * 2 + (lane >> 5);
    if (wid >= N) return;
    int l = lane & 31;
    int beg = rp[wid], end = rp[wid + 1];
    float a0 = 0.f, a1 = 0.f;
    for (int j = beg + l; j < end; j += 32) {
        int s = csr[j];
        float2 v = *(const float2*)(h2s + (size_t)s * 2);
        a0 += v.x; a1 += v.y;
    }
    a0 += __shfl_xor(a0, 1);  a1 += __shfl_xor(a1, 1);
    a0 += __shfl_xor(a0, 2);  a1 += __shfl_xor(a1, 2);
    a0 += __shfl_xor(a0, 4);  a1 += __shfl_xor(a1, 4);
    a0 += __shfl_xor(a0, 8);  a1 += __shfl_xor(a1, 8);
    a0 += __shfl_xor(a0, 16); a1 += __shfl_xor(a1, 16);
    if (l == 0) {
        float di = dinv[wid];
        float2 sv = *(const float2*)(h2s + (size_t)wid * 2);
        *(float2*)(out + (size_t)wid * 2) =
            make_float2(fmaf(di, a0 + sv.x, b2[0]), fmaf(di, a1 + sv.y, b2[1]));
    }
}

extern "C" void kernel_launch(void* const* d_in, const int* in_sizes, int n_in,
                              void* d_out, int out_size, void* d_ws, size_t ws_size,
                              hipStream_t stream) {
    const float* x  = (const float*)d_in[0];
    const int*   ei = (const int*)d_in[1];
    const float* W1 = (const float*)d_in[2];
    const float* b1 = (const float*)d_in[3];
    const float* W2 = (const float*)d_in[4];
    const float* b2 = (const float*)d_in[5];
    float* out = (float*)d_out;

    const int N = in_sizes[0] / 128;      // 100000
    const int E = in_sizes[1] / 2;        // 3200000
    const int NBUK = (N + 255) / 256;     // 391 (<= 512)
    const int NPB  = (E + EPB - 1) / EPB; // 391

    char* ws = (char*)d_ws;
    size_t off = 0;
    auto alloc = [&](size_t bytes) {
        void* p = ws + off;
        off = (off + bytes + 255) & ~(size_t)255;
        return p;
    };
    u32*   part  = (u32*)alloc((size_t)NBUK * RCAP * 4); // strided regions
    u32*   csr   = (u32*)alloc((size_t)E * 4);           // dense sorted
    int*   rp    = (int*)alloc((size_t)(N + 1) * 4);
    float* dinv  = (float*)alloc((size_t)N * 4);
    u16*   hs    = (u16*)alloc((size_t)N * 16 * 2);      // bf16
    float* h2s   = (float*)alloc((size_t)N * 2 * 4);
    int*   gcur  = (int*)alloc((size_t)NBUK * 4);

    k_binit  <<<dim3(1),    dim3(512), 0, stream>>>(gcur, NBUK);
    k_scatter<<<dim3(NPB),  dim3(512), 0, stream>>>(ei, gcur, part, E, NBUK);
    k_fillB  <<<dim3(NBUK), dim3(512), 0, stream>>>(part, gcur, csr, rp, dinv, N, E, NBUK);
    k_xw1    <<<dim3((N * 4 + 255) / 256), dim3(256), 0, stream>>>(x, W1, dinv, hs, N);
    k_agg1h2 <<<dim3((N + 3) / 4), dim3(256), 0, stream>>>(rp, (const int*)csr, hs, dinv, W2, b1, h2s, N);
    k_agg2   <<<dim3((N + 7) / 8), dim3(256), 0, stream>>>(rp, (const int*)csr, h2s, dinv, b2, out, N);
}

// Round 9
// 188.333 us; speedup vs baseline: 1.1242x; 1.1242x over previous
//
#include <hip/hip_runtime.h>

// GCN 2-layer forward, N=100000, E=3200000, 128->16->2.
// Session-2 round-8: REVERT of r7's agg restructure (regressed 189.1->211.7;
// k_agg1h2 measured 54.6us, VALUBusy 52%, HBM 6%, Occ 71%). Counter-refuted
// theory: at 71% occupancy gather latency was ALREADY hidden by TLP; the
// 1-node/wave form traded hidden latency for un-hidden VALU (5-stage x8-acc
// shuffle tree per node = 6.7x reduction work, epilogue x4).
// LESSON: gather-reduce at high occupancy wants many nodes/wave + shallow
// reduce trees; check OccupancyPercent before diagnosing latency-bound.
// KEPT from r7: bscan merged into fillB (6 launches) -- this round is the
// clean A/B for that merge vs the 189.1 r5 state.
// Validated and kept: fixed-stride regions (RCAP=12288), register-staged
// single-pass scatter, uint4 fillB passes, K-split k_xw1, bf16 hs,
// 4-nodes/wave agg kernels (2x16B halves x 4 groups).
// LESSONS: hot-address global atomicAdd serializes (~23G/s); LDS-atomic
// aggregation 8x worse than sorted gather.
// Algebra: hs = (x@W1)*dinv;
//   h1[d]  = relu(dinv[d]*(sum_nbr hs + hs[d]) + b1), W2 fused -> h2s
//   out[d] = dinv[d]*(sum_nbr h2s + h2s[d]) + b2

#define EPB  8192    // edges per partition block
#define RCAP 12288   // per-bucket region capacity (mean 8192, sigma~90)
#define CAP  16384   // LDS slots per bucket in k_fillB

typedef unsigned int u32;
typedef unsigned short u16;

__device__ __forceinline__ float bflo(u32 u) { return __uint_as_float(u << 16); }
__device__ __forceinline__ float bfhi(u32 u) { return __uint_as_float(u & 0xffff0000u); }
__device__ __forceinline__ u32 pack_bf2(float a, float b) {   // RNE
    u32 ua = __float_as_uint(a); ua = (ua + 0x7fffu + ((ua >> 16) & 1u)) >> 16;
    u32 ub = __float_as_uint(b); ub = (ub + 0x7fffu + ((ub >> 16) & 1u)) >> 16;
    return ua | (ub << 16);
}

// ---------------- init bucket region cursors ----------------
__global__ __launch_bounds__(512) void k_binit(int* __restrict__ gcur, int NBUK) {
    int t = threadIdx.x;
    if (t < NBUK) gcur[t] = t * RCAP;
}

// ---------------- single-pass partition: count+scan+reserve+place ----------
// Edges staged in registers (8x int4) across the scan -> no second global read.
__global__ __launch_bounds__(512) void k_scatter(const int* __restrict__ ei,
                                                 int* __restrict__ gcur,
                                                 u32* __restrict__ part,
                                                 int E, int NBUK) {
    __shared__ int hist[512];   // counts -> scan -> placement cursors
    __shared__ int rbase[512];  // global addr = rbase[b] + local slot j
    __shared__ u32 buf[EPB];
    __shared__ u16 bkt[EPB];
    int tid = threadIdx.x;
    hist[tid] = 0;
    __syncthreads();
    int base = blockIdx.x * EPB;
    int end = base + EPB; if (end > E) end = E;
    int cnt = end - base;
    int nv = cnt >> 2;
    const int4* s4p = (const int4*)(ei + base);
    const int4* d4p = (const int4*)(ei + E + base);
    int4 s4[4], d4[4];
    #pragma unroll
    for (int k = 0; k < 4; ++k) {
        int idx = tid + (k << 9);
        if (idx < nv) {
            s4[k] = s4p[idx];
            d4[k] = d4p[idx];
            atomicAdd(&hist[d4[k].x >> 8], 1);
            atomicAdd(&hist[d4[k].y >> 8], 1);
            atomicAdd(&hist[d4[k].z >> 8], 1);
            atomicAdd(&hist[d4[k].w >> 8], 1);
        }
    }
    for (int e = base + (nv << 2) + tid; e < end; e += 512)   // tail (cnt%4)
        atomicAdd(&hist[ei[E + e] >> 8], 1);
    __syncthreads();
    int v = hist[tid];
    __syncthreads();
    for (int o = 1; o < 512; o <<= 1) {                       // in-place scan
        int t = (tid >= o) ? hist[tid - o] : 0;
        __syncthreads();
        hist[tid] += t;
        __syncthreads();
    }
    int excl = hist[tid] - v;
    int rb = 0;
    if (tid < NBUK && v > 0) rb = atomicAdd(&gcur[tid], v);   // reserve run
    rbase[tid] = rb - excl;
    __syncthreads();
    hist[tid] = excl;            // placement cursor (own slot only)
    __syncthreads();
    #pragma unroll
    for (int k = 0; k < 4; ++k) {
        int idx = tid + (k << 9);
        if (idx < nv) {
            int b, pos;
            b = d4[k].x >> 8; pos = atomicAdd(&hist[b], 1);
            buf[pos] = ((u32)(d4[k].x & 255) << 24) | (u32)s4[k].x; bkt[pos] = (u16)b;
            b = d4[k].y >> 8; pos = atomicAdd(&hist[b], 1);
            buf[pos] = ((u32)(d4[k].y & 255) << 24) | (u32)s4[k].y; bkt[pos] = (u16)b;
            b = d4[k].z >> 8; pos = atomicAdd(&hist[b], 1);
            buf[pos] = ((u32)(d4[k].z & 255) << 24) | (u32)s4[k].z; bkt[pos] = (u16)b;
            b = d4[k].w >> 8; pos = atomicAdd(&hist[b], 1);
            buf[pos] = ((u32)(d4[k].w & 255) << 24) | (u32)s4[k].w; bkt[pos] = (u16)b;
        }
    }
    for (int e = base + (nv << 2) + tid; e < end; e += 512) { // tail re-read
        int s = ei[e], d = ei[E + e];
        int b = d >> 8;
        int pos = atomicAdd(&hist[b], 1);
        buf[pos] = ((u32)(d & 255) << 24) | (u32)s;
        bkt[pos] = (u16)b;
    }
    __syncthreads();
    for (int j = tid; j < cnt; j += 512)
        part[rbase[bkt[j]] + j] = buf[j];                     // ~coalesced runs
}

// ---------------- per-bucket sort by dst; region -> dense csr ---------------
// In-kernel bucket scan (bscan merged); both region passes uint4-vectorized.
__global__ __launch_bounds__(512) void k_fillB(const u32* __restrict__ part,
                                               const int* __restrict__ gcur,
                                               u32* __restrict__ csr,
                                               int* __restrict__ rp,
                                               float* __restrict__ dinv,
                                               int N, int E, int NBUK) {
    __shared__ int hist[256];
    __shared__ int ofs[256];
    __shared__ int bs[512];      // bucket-count scan
    __shared__ u32 srcbuf[CAP];
    int b = blockIdx.x, tid = threadIdx.x;
    if (b == 0 && tid == 0) rp[N] = E;
    int vb = (tid < NBUK) ? (gcur[tid] - tid * RCAP) : 0;
    bs[tid] = vb;
    if (tid < 256) hist[tid] = 0;
    __syncthreads();
    for (int o = 1; o < 512; o <<= 1) {
        int t = (tid >= o) ? bs[tid - o] : 0;
        __syncthreads();
        bs[tid] += t;
        __syncthreads();
    }
    int cnt = gcur[b] - b * RCAP;
    int base_w = bs[b] - cnt;              // dense write base
    int base_r = b * RCAP;                 // region read base (16B aligned)
    int nv = cnt >> 2;
    const uint4* p4 = (const uint4*)(part + base_r);
    for (int t = tid; t < nv; t += 512) {
        uint4 pv = p4[t];
        atomicAdd(&hist[pv.x >> 24], 1);
        atomicAdd(&hist[pv.y >> 24], 1);
        atomicAdd(&hist[pv.z >> 24], 1);
        atomicAdd(&hist[pv.w >> 24], 1);
    }
    for (int j = (nv << 2) + tid; j < cnt; j += 512)
        atomicAdd(&hist[part[base_r + j] >> 24], 1);
    __syncthreads();
    int v = 0;
    if (tid < 256) { v = hist[tid]; ofs[tid] = v; }
    __syncthreads();
    for (int o = 1; o < 256; o <<= 1) {
        int t = 0;
        if (tid < 256 && tid >= o) t = ofs[tid - o];
        __syncthreads();
        if (tid < 256) ofs[tid] += t;
        __syncthreads();
    }
    int excl = 0;
    if (tid < 256) { excl = ofs[tid] - v; hist[tid] = excl; }
    __syncthreads();
    for (int t = tid; t < nv; t += 512) {
        uint4 pv = p4[t];
        int pos;
        pos = atomicAdd(&hist[pv.x >> 24], 1);
        if (pos < CAP) srcbuf[pos] = pv.x & 0xFFFFFFu;
        pos = atomicAdd(&hist[pv.y >> 24], 1);
        if (pos < CAP) srcbuf[pos] = pv.y & 0xFFFFFFu;
        pos = atomicAdd(&hist[pv.z >> 24], 1);
        if (pos < CAP) srcbuf[pos] = pv.z & 0xFFFFFFu;
        pos = atomicAdd(&hist[pv.w >> 24], 1);
        if (pos < CAP) srcbuf[pos] = pv.w & 0xFFFFFFu;
    }
    for (int j = (nv << 2) + tid; j < cnt; j += 512) {
        u32 pv = part[base_r + j];
        int pos = atomicAdd(&hist[pv >> 24], 1);
        if (pos < CAP) srcbuf[pos] = pv & 0xFFFFFFu;
    }
    __syncthreads();
    for (int j = tid; j < cnt; j += 512)
        csr[base_w + j] = srcbuf[j];       // coalesced dense write
    int d = b * 256 + tid;
    if (tid < 256 && d < N) {
        rp[d] = base_w + excl;
        dinv[d] = rsqrtf((float)(v + 1));  // +1 self loop
    }
}

// ---------------- hs[N,16](bf16) = (x@W1)*dinv, K-split, x read once ---------
__global__ __launch_bounds__(256) void k_xw1(const float* __restrict__ x,
                                             const float* __restrict__ W1,
                                             const float* __restrict__ dinv,
                                             u16* __restrict__ hs, int N) {
    __shared__ float w[4 * 516];   // section q = W1 rows 32q..32q+31; +4 pad
    int tid = threadIdx.x;
    for (int t = tid; t < 2048; t += 256)
        w[(t >> 9) * 516 + (t & 511)] = W1[t];
    __syncthreads();
    int t = blockIdx.x * 256 + tid;
    int n = t >> 2, q = t & 3;
    if (n >= N) return;
    const float4* xr = (const float4*)(x + (size_t)n * 128 + q * 32);  // 8 f4
    const float* ws = w + q * 516;
    float acc[16];
    #pragma unroll
    for (int c = 0; c < 16; ++c) acc[c] = 0.f;
    #pragma unroll
    for (int i = 0; i < 8; ++i) {
        float4 u = xr[i];
        const float4* wf = (const float4*)(ws + i * 64);  // rows 4i..4i+3
        #pragma unroll
        for (int c4 = 0; c4 < 4; ++c4) {
            float4 wa = wf[c4];
            float4 wb = wf[4 + c4];
            float4 wc = wf[8 + c4];
            float4 wd = wf[12 + c4];
            int c = c4 * 4;
            acc[c+0] = fmaf(u.x, wa.x, acc[c+0]); acc[c+1] = fmaf(u.x, wa.y, acc[c+1]);
            acc[c+2] = fmaf(u.x, wa.z, acc[c+2]); acc[c+3] = fmaf(u.x, wa.w, acc[c+3]);
            acc[c+0] = fmaf(u.y, wb.x, acc[c+0]); acc[c+1] = fmaf(u.y, wb.y, acc[c+1]);
            acc[c+2] = fmaf(u.y, wb.z, acc[c+2]); acc[c+3] = fmaf(u.y, wb.w, acc[c+3]);
            acc[c+0] = fmaf(u.z, wc.x, acc[c+0]); acc[c+1] = fmaf(u.z, wc.y, acc[c+1]);
            acc[c+2] = fmaf(u.z, wc.z, acc[c+2]); acc[c+3] = fmaf(u.z, wc.w, acc[c+3]);
            acc[c+0] = fmaf(u.w, wd.x, acc[c+0]); acc[c+1] = fmaf(u.w, wd.y, acc[c+1]);
            acc[c+2] = fmaf(u.w, wd.z, acc[c+2]); acc[c+3] = fmaf(u.w, wd.w, acc[c+3]);
        }
    }
    #pragma unroll
    for (int c = 0; c < 16; ++c) {
        acc[c] += __shfl_xor(acc[c], 1);
        acc[c] += __shfl_xor(acc[c], 2);
    }
    float di = dinv[n];
    uint2 o;
    o.x = pack_bf2(acc[4*q+0] * di, acc[4*q+1] * di);
    o.y = pack_bf2(acc[4*q+2] * di, acc[4*q+3] * di);
    ((uint2*)(hs + (size_t)n * 16))[q] = o;
}

// ---------------- fused layer-1 gather + ReLU + W2 projection ----------------
// 4 nodes/wave; 16 lanes/node = 2 halves (16B uint4 each) x 8 edge groups.
__global__ __launch_bounds__(256) void k_agg1h2(const int* __restrict__ rp,
                                                const int* __restrict__ csr,
                                                const u16* __restrict__ hs,
                                                const float* __restrict__ dinv,
                                                const float* __restrict__ W2,
                                                const float* __restrict__ b1,
                                                float* __restrict__ h2s, int N) {
    int lane = threadIdx.x & 63;
    int wid = blockIdx.x * 16 + (threadIdx.x >> 6) * 4 + (lane >> 4);
    if (wid >= N) return;
    int l = lane & 15;
    int half = l & 1, g = l >> 1;                  // 16B half, edge group
    int beg = rp[wid], end = rp[wid + 1];
    float a0 = 0.f, a1 = 0.f, a2 = 0.f, a3 = 0.f;
    float a4 = 0.f, a5 = 0.f, a6 = 0.f, a7 = 0.f;
    for (int j = beg + g; j < end; j += 8) {
        int s = csr[j];
        uint4 u = ((const uint4*)(hs + (size_t)s * 16))[half];
        a0 += bflo(u.x); a1 += bfhi(u.x);
        a2 += bflo(u.y); a3 += bfhi(u.y);
        a4 += bflo(u.z); a5 += bfhi(u.z);
        a6 += bflo(u.w); a7 += bfhi(u.w);
    }
    a0 += __shfl_xor(a0, 2); a1 += __shfl_xor(a1, 2);
    a2 += __shfl_xor(a2, 2); a3 += __shfl_xor(a3, 2);
    a4 += __shfl_xor(a4, 2); a5 += __shfl_xor(a5, 2);
    a6 += __shfl_xor(a6, 2); a7 += __shfl_xor(a7, 2);
    a0 += __shfl_xor(a0, 4); a1 += __shfl_xor(a1, 4);
    a2 += __shfl_xor(a2, 4); a3 += __shfl_xor(a3, 4);
    a4 += __shfl_xor(a4, 4); a5 += __shfl_xor(a5, 4);
    a6 += __shfl_xor(a6, 4); a7 += __shfl_xor(a7, 4);
    a0 += __shfl_xor(a0, 8); a1 += __shfl_xor(a1, 8);
    a2 += __shfl_xor(a2, 8); a3 += __shfl_xor(a3, 8);
    a4 += __shfl_xor(a4, 8); a5 += __shfl_xor(a5, 8);
    a6 += __shfl_xor(a6, 8); a7 += __shfl_xor(a7, 8);
    uint4 su = ((const uint4*)(hs + (size_t)wid * 16))[half];   // self term
    a0 += bflo(su.x); a1 += bfhi(su.x);
    a2 += bflo(su.y); a3 += bfhi(su.y);
    a4 += bflo(su.z); a5 += bfhi(su.z);
    a6 += bflo(su.w); a7 += bfhi(su.w);
    float di = dinv[wid];
    float4 bA = ((const float4*)b1)[half * 2];
    float4 bB = ((const float4*)b1)[half * 2 + 1];
    float v0 = fmaxf(fmaf(di, a0, bA.x), 0.f);
    float v1 = fmaxf(fmaf(di, a1, bA.y), 0.f);
    float v2 = fmaxf(fmaf(di, a2, bA.z), 0.f);
    float v3 = fmaxf(fmaf(di, a3, bA.w), 0.f);
    float v4 = fmaxf(fmaf(di, a4, bB.x), 0.f);
    float v5 = fmaxf(fmaf(di, a5, bB.y), 0.f);
    float v6 = fmaxf(fmaf(di, a6, bB.z), 0.f);
    float v7 = fmaxf(fmaf(di, a7, bB.w), 0.f);
    const float4* w4 = (const float4*)W2 + half * 4;   // rows half*8..+7
    float4 q0 = w4[0], q1 = w4[1], q2 = w4[2], q3 = w4[3];
    float p0 = v0*q0.x + v1*q0.z + v2*q1.x + v3*q1.z
             + v4*q2.x + v5*q2.z + v6*q3.x + v7*q3.z;
    float p1 = v0*q0.y + v1*q0.w + v2*q1.y + v3*q1.w
             + v4*q2.y + v5*q2.w + v6*q3.y + v7*q3.w;
    p0 += __shfl_xor(p0, 1); p1 += __shfl_xor(p1, 1);  // sum the two halves
    if (l == 0)
        *(float2*)(h2s + (size_t)wid * 2) = make_float2(p0 * di, p1 * di);
}

// ---------------- layer-2 gather -> out (4 nodes/wave, 16 lanes/node) --------
__global__ __launch_bounds__(256) void k_agg2(const int* __restrict__ rp,
                                              const int* __restrict__ csr,
                                              const float* __restrict__ h2s,
                                              const float* __restrict__ dinv,
                                              const float* __restrict__ b2,
                                              float* __restrict__ out, int N) {
    int lane = threadIdx.x & 63;
    int wid = blockIdx.x * 16 + (threadIdx.x >> 6) * 4 + (lane >> 4);
    if (wid >= N) return;
    int l = lane & 15;
    int beg = rp[wid], end = rp[wid + 1];
    float a0 = 0.f, a1 = 0.f;
    for (int j = beg + l; j < end; j += 16) {
        int s = csr[j];
        float2 v = *(const float2*)(h2s + (size_t)s * 2);
        a0 += v.x; a1 += v.y;
    }
    a0 += __shfl_xor(a0, 1); a1 += __shfl_xor(a1, 1);
    a0 += __shfl_xor(a0, 2); a1 += __shfl_xor(a1, 2);
    a0 += __shfl_xor(a0, 4); a1 += __shfl_xor(a1, 4);
    a0 += __shfl_xor(a0, 8); a1 += __shfl_xor(a1, 8);
    if (l == 0) {
        float di = dinv[wid];
        float2 sv = *(const float2*)(h2s + (size_t)wid * 2);
        *(float2*)(out + (size_t)wid * 2) =
            make_float2(fmaf(di, a0 + sv.x, b2[0]), fmaf(di, a1 + sv.y, b2[1]));
    }
}

extern "C" void kernel_launch(void* const* d_in, const int* in_sizes, int n_in,
                              void* d_out, int out_size, void* d_ws, size_t ws_size,
                              hipStream_t stream) {
    const float* x  = (const float*)d_in[0];
    const int*   ei = (const int*)d_in[1];
    const float* W1 = (const float*)d_in[2];
    const float* b1 = (const float*)d_in[3];
    const float* W2 = (const float*)d_in[4];
    const float* b2 = (const float*)d_in[5];
    float* out = (float*)d_out;

    const int N = in_sizes[0] / 128;      // 100000
    const int E = in_sizes[1] / 2;        // 3200000
    const int NBUK = (N + 255) / 256;     // 391 (<= 512)
    const int NPB  = (E + EPB - 1) / EPB; // 391

    char* ws = (char*)d_ws;
    size_t off = 0;
    auto alloc = [&](size_t bytes) {
        void* p = ws + off;
        off = (off + bytes + 255) & ~(size_t)255;
        return p;
    };
    u32*   part  = (u32*)alloc((size_t)NBUK * RCAP * 4); // strided regions
    u32*   csr   = (u32*)alloc((size_t)E * 4);           // dense sorted
    int*   rp    = (int*)alloc((size_t)(N + 1) * 4);
    float* dinv  = (float*)alloc((size_t)N * 4);
    u16*   hs    = (u16*)alloc((size_t)N * 16 * 2);      // bf16
    float* h2s   = (float*)alloc((size_t)N * 2 * 4);
    int*   gcur  = (int*)alloc((size_t)NBUK * 4);

    k_binit  <<<dim3(1),    dim3(512), 0, stream>>>(gcur, NBUK);
    k_scatter<<<dim3(NPB),  dim3(512), 0, stream>>>(ei, gcur, part, E, NBUK);
    k_fillB  <<<dim3(NBUK), dim3(512), 0, stream>>>(part, gcur, csr, rp, dinv, N, E, NBUK);
    k_xw1    <<<dim3((N * 4 + 255) / 256), dim3(256), 0, stream>>>(x, W1, dinv, hs, N);
    k_agg1h2 <<<dim3((N + 15) / 16), dim3(256), 0, stream>>>(rp, (const int*)csr, hs, dinv, W2, b1, h2s, N);
    k_agg2   <<<dim3((N + 15) / 16), dim3(256), 0, stream>>>(rp, (const int*)csr, h2s, dinv, b2, out, N);
}

// Round 11
// 179.176 us; speedup vs baseline: 1.1817x; 1.0511x over previous
//
#include <hip/hip_runtime.h>

// GCN 2-layer forward, N=100000, E=3200000, 128->16->2.
// Session-2 round-10: verbatim resubmit of round-9 source (round-10 bench
// was an infra failure: GPUAcquisitionTimeout -- code never ran).
// Round-9 change under test: TASK-PARALLEL FAT KERNEL. k_xw1 is
// data-independent of the CSR build, so it is fused into k_scatter by block
// role-split (blocks 0..NSCAT-1 scatter, rest compute hraw = x@W1 in f32,
// NO dinv). LDS via explicit union (52KB scatter / 8KB xw1). The *dinv +
// bf16 pack moves to k_fillB's tail where dinv is live in registers
// (+9.6MB stream, ~+2.5us, bit-identical f32 math). 6 -> 5 launches;
// xw1's ~23us hides under scatter's LDS-atomic latency.
// Risk noted: fat-kernel VGPR = max(scatter 40, xw1 ~60+); >64 drops
// scatter 3->2 blocks/CU -- overlap should still dominate.
// LESSONS: hot-address global atomicAdd serializes (~23G/s); LDS-atomic
// aggregation 8x worse than sorted gather; gather-reduce at high occupancy
// wants many nodes/wave + shallow reduce trees (r8: 1-node/wave = +22us).
// Algebra: hs = (x@W1)*dinv;
//   h1[d]  = relu(dinv[d]*(sum_nbr hs + hs[d]) + b1), W2 fused -> h2s
//   out[d] = dinv[d]*(sum_nbr h2s + h2s[d]) + b2

#define EPB  8192    // edges per partition block
#define RCAP 12288   // per-bucket region capacity (mean 8192, sigma~90)
#define CAP  16384   // LDS slots per bucket in k_fillB

typedef unsigned int u32;
typedef unsigned short u16;

__device__ __forceinline__ float bflo(u32 u) { return __uint_as_float(u << 16); }
__device__ __forceinline__ float bfhi(u32 u) { return __uint_as_float(u & 0xffff0000u); }
__device__ __forceinline__ u32 pack_bf2(float a, float b) {   // RNE
    u32 ua = __float_as_uint(a); ua = (ua + 0x7fffu + ((ua >> 16) & 1u)) >> 16;
    u32 ub = __float_as_uint(b); ub = (ub + 0x7fffu + ((ub >> 16) & 1u)) >> 16;
    return ua | (ub << 16);
}

// ---------------- init bucket region cursors ----------------
__global__ __launch_bounds__(512) void k_binit(int* __restrict__ gcur, int NBUK) {
    int t = threadIdx.x;
    if (t < NBUK) gcur[t] = t * RCAP;
}

// ---------------- FAT: partition (blocks < NSCAT) || hraw = x@W1 (rest) -----
__global__ __launch_bounds__(512) void k_fat(const int* __restrict__ ei,
                                             int* __restrict__ gcur,
                                             u32* __restrict__ part,
                                             const float* __restrict__ x,
                                             const float* __restrict__ W1,
                                             float* __restrict__ hraw,
                                             int E, int NBUK, int NSCAT, int N) {
    __shared__ union {
        struct { int hist[512]; int rbase[512]; u32 buf[EPB]; u16 bkt[EPB]; } s;
        float w[4 * 516];   // xw1: section q = W1 rows 32q..32q+31; +4 pad
    } sm;
    int tid = threadIdx.x;
    if ((int)blockIdx.x < NSCAT) {
        // ---- scatter: count+scan+reserve+place, edges staged in registers --
        sm.s.hist[tid] = 0;
        __syncthreads();
        int base = blockIdx.x * EPB;
        int end = base + EPB; if (end > E) end = E;
        int cnt = end - base;
        int nv = cnt >> 2;
        const int4* s4p = (const int4*)(ei + base);
        const int4* d4p = (const int4*)(ei + E + base);
        int4 s4[4], d4[4];
        #pragma unroll
        for (int k = 0; k < 4; ++k) {
            int idx = tid + (k << 9);
            if (idx < nv) {
                s4[k] = s4p[idx];
                d4[k] = d4p[idx];
                atomicAdd(&sm.s.hist[d4[k].x >> 8], 1);
                atomicAdd(&sm.s.hist[d4[k].y >> 8], 1);
                atomicAdd(&sm.s.hist[d4[k].z >> 8], 1);
                atomicAdd(&sm.s.hist[d4[k].w >> 8], 1);
            }
        }
        for (int e = base + (nv << 2) + tid; e < end; e += 512)  // tail
            atomicAdd(&sm.s.hist[ei[E + e] >> 8], 1);
        __syncthreads();
        int v = sm.s.hist[tid];
        __syncthreads();
        for (int o = 1; o < 512; o <<= 1) {                      // in-place scan
            int t = (tid >= o) ? sm.s.hist[tid - o] : 0;
            __syncthreads();
            sm.s.hist[tid] += t;
            __syncthreads();
        }
        int excl = sm.s.hist[tid] - v;
        int rb = 0;
        if (tid < NBUK && v > 0) rb = atomicAdd(&gcur[tid], v);  // reserve run
        sm.s.rbase[tid] = rb - excl;
        __syncthreads();
        sm.s.hist[tid] = excl;        // placement cursor (own slot only)
        __syncthreads();
        #pragma unroll
        for (int k = 0; k < 4; ++k) {
            int idx = tid + (k << 9);
            if (idx < nv) {
                int b, pos;
                b = d4[k].x >> 8; pos = atomicAdd(&sm.s.hist[b], 1);
                sm.s.buf[pos] = ((u32)(d4[k].x & 255) << 24) | (u32)s4[k].x; sm.s.bkt[pos] = (u16)b;
                b = d4[k].y >> 8; pos = atomicAdd(&sm.s.hist[b], 1);
                sm.s.buf[pos] = ((u32)(d4[k].y & 255) << 24) | (u32)s4[k].y; sm.s.bkt[pos] = (u16)b;
                b = d4[k].z >> 8; pos = atomicAdd(&sm.s.hist[b], 1);
                sm.s.buf[pos] = ((u32)(d4[k].z & 255) << 24) | (u32)s4[k].z; sm.s.bkt[pos] = (u16)b;
                b = d4[k].w >> 8; pos = atomicAdd(&sm.s.hist[b], 1);
                sm.s.buf[pos] = ((u32)(d4[k].w & 255) << 24) | (u32)s4[k].w; sm.s.bkt[pos] = (u16)b;
            }
        }
        for (int e = base + (nv << 2) + tid; e < end; e += 512) { // tail re-read
            int s = ei[e], d = ei[E + e];
            int b = d >> 8;
            int pos = atomicAdd(&sm.s.hist[b], 1);
            sm.s.buf[pos] = ((u32)(d & 255) << 24) | (u32)s;
            sm.s.bkt[pos] = (u16)b;
        }
        __syncthreads();
        for (int j = tid; j < cnt; j += 512)
            part[sm.s.rbase[sm.s.bkt[j]] + j] = sm.s.buf[j];     // ~coalesced
    } else {
        // ---- xw1_raw: hraw[n][16] = x[n]@W1 (f32, no dinv), K-split x4 -----
        for (int t = tid; t < 2048; t += 512)
            sm.w[(t >> 9) * 516 + (t & 511)] = W1[t];
        __syncthreads();
        int t = ((int)blockIdx.x - NSCAT) * 512 + tid;
        int n = t >> 2, q = t & 3;
        if (n >= N) return;
        const float4* xr = (const float4*)(x + (size_t)n * 128 + q * 32);  // 8 f4
        const float* ws = sm.w + q * 516;
        float acc[16];
        #pragma unroll
        for (int c = 0; c < 16; ++c) acc[c] = 0.f;
        #pragma unroll
        for (int i = 0; i < 8; ++i) {
            float4 u = xr[i];
            const float4* wf = (const float4*)(ws + i * 64);  // rows 4i..4i+3
            #pragma unroll
            for (int c4 = 0; c4 < 4; ++c4) {
                float4 wa = wf[c4];
                float4 wb = wf[4 + c4];
                float4 wc = wf[8 + c4];
                float4 wd = wf[12 + c4];
                int c = c4 * 4;
                acc[c+0] = fmaf(u.x, wa.x, acc[c+0]); acc[c+1] = fmaf(u.x, wa.y, acc[c+1]);
                acc[c+2] = fmaf(u.x, wa.z, acc[c+2]); acc[c+3] = fmaf(u.x, wa.w, acc[c+3]);
                acc[c+0] = fmaf(u.y, wb.x, acc[c+0]); acc[c+1] = fmaf(u.y, wb.y, acc[c+1]);
                acc[c+2] = fmaf(u.y, wb.z, acc[c+2]); acc[c+3] = fmaf(u.y, wb.w, acc[c+3]);
                acc[c+0] = fmaf(u.z, wc.x, acc[c+0]); acc[c+1] = fmaf(u.z, wc.y, acc[c+1]);
                acc[c+2] = fmaf(u.z, wc.z, acc[c+2]); acc[c+3] = fmaf(u.z, wc.w, acc[c+3]);
                acc[c+0] = fmaf(u.w, wd.x, acc[c+0]); acc[c+1] = fmaf(u.w, wd.y, acc[c+1]);
                acc[c+2] = fmaf(u.w, wd.z, acc[c+2]); acc[c+3] = fmaf(u.w, wd.w, acc[c+3]);
            }
        }
        #pragma unroll
        for (int c = 0; c < 16; ++c) {
            acc[c] += __shfl_xor(acc[c], 1);
            acc[c] += __shfl_xor(acc[c], 2);
        }
        ((float4*)(hraw + (size_t)n * 16))[q] =
            make_float4(acc[4*q+0], acc[4*q+1], acc[4*q+2], acc[4*q+3]);
    }
}

// ---------------- per-bucket sort by dst; region -> dense csr ---------------
// In-kernel bucket scan; uint4 passes; tail: hs = hraw*dinv (bf16 pack).
__global__ __launch_bounds__(512) void k_fillB(const u32* __restrict__ part,
                                               const int* __restrict__ gcur,
                                               u32* __restrict__ csr,
                                               int* __restrict__ rp,
                                               float* __restrict__ dinv,
                                               const float* __restrict__ hraw,
                                               u16* __restrict__ hs,
                                               int N, int E, int NBUK) {
    __shared__ int hist[256];
    __shared__ int ofs[256];
    __shared__ int bs[512];      // bucket-count scan
    __shared__ u32 srcbuf[CAP];
    int b = blockIdx.x, tid = threadIdx.x;
    if (b == 0 && tid == 0) rp[N] = E;
    int vb = (tid < NBUK) ? (gcur[tid] - tid * RCAP) : 0;
    bs[tid] = vb;
    if (tid < 256) hist[tid] = 0;
    __syncthreads();
    for (int o = 1; o < 512; o <<= 1) {
        int t = (tid >= o) ? bs[tid - o] : 0;
        __syncthreads();
        bs[tid] += t;
        __syncthreads();
    }
    int cnt = gcur[b] - b * RCAP;
    int base_w = bs[b] - cnt;              // dense write base
    int base_r = b * RCAP;                 // region read base (16B aligned)
    int nv = cnt >> 2;
    const uint4* p4 = (const uint4*)(part + base_r);
    for (int t = tid; t < nv; t += 512) {
        uint4 pv = p4[t];
        atomicAdd(&hist[pv.x >> 24], 1);
        atomicAdd(&hist[pv.y >> 24], 1);
        atomicAdd(&hist[pv.z >> 24], 1);
        atomicAdd(&hist[pv.w >> 24], 1);
    }
    for (int j = (nv << 2) + tid; j < cnt; j += 512)
        atomicAdd(&hist[part[base_r + j] >> 24], 1);
    __syncthreads();
    int v = 0;
    if (tid < 256) { v = hist[tid]; ofs[tid] = v; }
    __syncthreads();
    for (int o = 1; o < 256; o <<= 1) {
        int t = 0;
        if (tid < 256 && tid >= o) t = ofs[tid - o];
        __syncthreads();
        if (tid < 256) ofs[tid] += t;
        __syncthreads();
    }
    int excl = 0;
    if (tid < 256) { excl = ofs[tid] - v; hist[tid] = excl; }
    __syncthreads();
    for (int t = tid; t < nv; t += 512) {
        uint4 pv = p4[t];
        int pos;
        pos = atomicAdd(&hist[pv.x >> 24], 1);
        if (pos < CAP) srcbuf[pos] = pv.x & 0xFFFFFFu;
        pos = atomicAdd(&hist[pv.y >> 24], 1);
        if (pos < CAP) srcbuf[pos] = pv.y & 0xFFFFFFu;
        pos = atomicAdd(&hist[pv.z >> 24], 1);
        if (pos < CAP) srcbuf[pos] = pv.z & 0xFFFFFFu;
        pos = atomicAdd(&hist[pv.w >> 24], 1);
        if (pos < CAP) srcbuf[pos] = pv.w & 0xFFFFFFu;
    }
    for (int j = (nv << 2) + tid; j < cnt; j += 512) {
        u32 pv = part[base_r + j];
        int pos = atomicAdd(&hist[pv >> 24], 1);
        if (pos < CAP) srcbuf[pos] = pv & 0xFFFFFFu;
    }
    __syncthreads();
    for (int j = tid; j < cnt; j += 512)
        csr[base_w + j] = srcbuf[j];       // coalesced dense write
    int d = b * 256 + tid;
    if (tid < 256 && d < N) {
        rp[d] = base_w + excl;
        float dval = rsqrtf((float)(v + 1));   // +1 self loop
        dinv[d] = dval;
        ((float*)ofs)[tid] = dval;             // stash for scale step
    }
    __syncthreads();
    // ---- hs[dn] = bf16(hraw[dn] * dinv[dn]); 2 threads/node, 16B halves ----
    int dn = b * 256 + (tid >> 1);
    if (dn < N) {
        float di = ((float*)ofs)[tid >> 1];
        int h = tid & 1;
        const float4* hr = (const float4*)(hraw + (size_t)dn * 16);
        float4 A = hr[h * 2], B = hr[h * 2 + 1];
        uint4 o;
        o.x = pack_bf2(A.x * di, A.y * di);
        o.y = pack_bf2(A.z * di, A.w * di);
        o.z = pack_bf2(B.x * di, B.y * di);
        o.w = pack_bf2(B.z * di, B.w * di);
        ((uint4*)(hs + (size_t)dn * 16))[h] = o;
    }
}

// ---------------- fused layer-1 gather + ReLU + W2 projection ----------------
// 4 nodes/wave; 16 lanes/node = 2 halves (16B uint4 each) x 8 edge groups.
__global__ __launch_bounds__(256) void k_agg1h2(const int* __restrict__ rp,
                                                const int* __restrict__ csr,
                                                const u16* __restrict__ hs,
                                                const float* __restrict__ dinv,
                                                const float* __restrict__ W2,
                                                const float* __restrict__ b1,
                                                float* __restrict__ h2s, int N) {
    int lane = threadIdx.x & 63;
    int wid = blockIdx.x * 16 + (threadIdx.x >> 6) * 4 + (lane >> 4);
    if (wid >= N) return;
    int l = lane & 15;
    int half = l & 1, g = l >> 1;                  // 16B half, edge group
    int beg = rp[wid], end = rp[wid + 1];
    float a0 = 0.f, a1 = 0.f, a2 = 0.f, a3 = 0.f;
    float a4 = 0.f, a5 = 0.f, a6 = 0.f, a7 = 0.f;
    for (int j = beg + g; j < end; j += 8) {
        int s = csr[j];
        uint4 u = ((const uint4*)(hs + (size_t)s * 16))[half];
        a0 += bflo(u.x); a1 += bfhi(u.x);
        a2 += bflo(u.y); a3 += bfhi(u.y);
        a4 += bflo(u.z); a5 += bfhi(u.z);
        a6 += bflo(u.w); a7 += bfhi(u.w);
    }
    a0 += __shfl_xor(a0, 2); a1 += __shfl_xor(a1, 2);
    a2 += __shfl_xor(a2, 2); a3 += __shfl_xor(a3, 2);
    a4 += __shfl_xor(a4, 2); a5 += __shfl_xor(a5, 2);
    a6 += __shfl_xor(a6, 2); a7 += __shfl_xor(a7, 2);
    a0 += __shfl_xor(a0, 4); a1 += __shfl_xor(a1, 4);
    a2 += __shfl_xor(a2, 4); a3 += __shfl_xor(a3, 4);
    a4 += __shfl_xor(a4, 4); a5 += __shfl_xor(a5, 4);
    a6 += __shfl_xor(a6, 4); a7 += __shfl_xor(a7, 4);
    a0 += __shfl_xor(a0, 8); a1 += __shfl_xor(a1, 8);
    a2 += __shfl_xor(a2, 8); a3 += __shfl_xor(a3, 8);
    a4 += __shfl_xor(a4, 8); a5 += __shfl_xor(a5, 8);
    a6 += __shfl_xor(a6, 8); a7 += __shfl_xor(a7, 8);
    uint4 su = ((const uint4*)(hs + (size_t)wid * 16))[half];   // self term
    a0 += bflo(su.x); a1 += bfhi(su.x);
    a2 += bflo(su.y); a3 += bfhi(su.y);
    a4 += bflo(su.z); a5 += bfhi(su.z);
    a6 += bflo(su.w); a7 += bfhi(su.w);
    float di = dinv[wid];
    float4 bA = ((const float4*)b1)[half * 2];
    float4 bB = ((const float4*)b1)[half * 2 + 1];
    float v0 = fmaxf(fmaf(di, a0, bA.x), 0.f);
    float v1 = fmaxf(fmaf(di, a1, bA.y), 0.f);
    float v2 = fmaxf(fmaf(di, a2, bA.z), 0.f);
    float v3 = fmaxf(fmaf(di, a3, bA.w), 0.f);
    float v4 = fmaxf(fmaf(di, a4, bB.x), 0.f);
    float v5 = fmaxf(fmaf(di, a5, bB.y), 0.f);
    float v6 = fmaxf(fmaf(di, a6, bB.z), 0.f);
    float v7 = fmaxf(fmaf(di, a7, bB.w), 0.f);
    const float4* w4 = (const float4*)W2 + half * 4;   // rows half*8..+7
    float4 q0 = w4[0], q1 = w4[1], q2 = w4[2], q3 = w4[3];
    float p0 = v0*q0.x + v1*q0.z + v2*q1.x + v3*q1.z
             + v4*q2.x + v5*q2.z + v6*q3.x + v7*q3.z;
    float p1 = v0*q0.y + v1*q0.w + v2*q1.y + v3*q1.w
             + v4*q2.y + v5*q2.w + v6*q3.y + v7*q3.w;
    p0 += __shfl_xor(p0, 1); p1 += __shfl_xor(p1, 1);  // sum the two halves
    if (l == 0)
        *(float2*)(h2s + (size_t)wid * 2) = make_float2(p0 * di, p1 * di);
}

// ---------------- layer-2 gather -> out (4 nodes/wave, 16 lanes/node) --------
__global__ __launch_bounds__(256) void k_agg2(const int* __restrict__ rp,
                                              const int* __restrict__ csr,
                                              const float* __restrict__ h2s,
                                              const float* __restrict__ dinv,
                                              const float* __restrict__ b2,
                                              float* __restrict__ out, int N) {
    int lane = threadIdx.x & 63;
    int wid = blockIdx.x * 16 + (threadIdx.x >> 6) * 4 + (lane >> 4);
    if (wid >= N) return;
    int l = lane & 15;
    int beg = rp[wid], end = rp[wid + 1];
    float a0 = 0.f, a1 = 0.f;
    for (int j = beg + l; j < end; j += 16) {
        int s = csr[j];
        float2 v = *(const float2*)(h2s + (size_t)s * 2);
        a0 += v.x; a1 += v.y;
    }
    a0 += __shfl_xor(a0, 1); a1 += __shfl_xor(a1, 1);
    a0 += __shfl_xor(a0, 2); a1 += __shfl_xor(a1, 2);
    a0 += __shfl_xor(a0, 4); a1 += __shfl_xor(a1, 4);
    a0 += __shfl_xor(a0, 8); a1 += __shfl_xor(a1, 8);
    if (l == 0) {
        float di = dinv[wid];
        float2 sv = *(const float2*)(h2s + (size_t)wid * 2);
        *(float2*)(out + (size_t)wid * 2) =
            make_float2(fmaf(di, a0 + sv.x, b2[0]), fmaf(di, a1 + sv.y, b2[1]));
    }
}

extern "C" void kernel_launch(void* const* d_in, const int* in_sizes, int n_in,
                              void* d_out, int out_size, void* d_ws, size_t ws_size,
                              hipStream_t stream) {
    const float* x  = (const float*)d_in[0];
    const int*   ei = (const int*)d_in[1];
    const float* W1 = (const float*)d_in[2];
    const float* b1 = (const float*)d_in[3];
    const float* W2 = (const float*)d_in[4];
    const float* b2 = (const float*)d_in[5];
    float* out = (float*)d_out;

    const int N = in_sizes[0] / 128;      // 100000
    const int E = in_sizes[1] / 2;        // 3200000
    const int NBUK = (N + 255) / 256;     // 391 (<= 512)
    const int NPB  = (E + EPB - 1) / EPB; // 391 (scatter blocks)
    const int NXW  = (N * 4 + 511) / 512; // 782 (xw1 blocks)

    char* ws = (char*)d_ws;
    size_t off = 0;
    auto alloc = [&](size_t bytes) {
        void* p = ws + off;
        off = (off + bytes + 255) & ~(size_t)255;
        return p;
    };
    u32*   part  = (u32*)alloc((size_t)NBUK * RCAP * 4); // strided regions
    u32*   csr   = (u32*)alloc((size_t)E * 4);           // dense sorted
    int*   rp    = (int*)alloc((size_t)(N + 1) * 4);
    float* dinv  = (float*)alloc((size_t)N * 4);
    float* hraw  = (float*)alloc((size_t)N * 16 * 4);    // f32 x@W1, no dinv
    u16*   hs    = (u16*)alloc((size_t)N * 16 * 2);      // bf16 scaled
    float* h2s   = (float*)alloc((size_t)N * 2 * 4);
    int*   gcur  = (int*)alloc((size_t)NBUK * 4);

    k_binit  <<<dim3(1),          dim3(512), 0, stream>>>(gcur, NBUK);
    k_fat    <<<dim3(NPB + NXW),  dim3(512), 0, stream>>>(ei, gcur, part, x, W1, hraw, E, NBUK, NPB, N);
    k_fillB  <<<dim3(NBUK),       dim3(512), 0, stream>>>(part, gcur, csr, rp, dinv, hraw, hs, N, E, NBUK);
    k_agg1h2 <<<dim3((N + 15) / 16), dim3(256), 0, stream>>>(rp, (const int*)csr, hs, dinv, W2, b1, h2s, N);
    k_agg2   <<<dim3((N + 15) / 16), dim3(256), 0, stream>>>(rp, (const int*)csr, h2s, dinv, b2, out, N);
}